// Round 1
// baseline (455.669 us; speedup 1.0000x reference)
//
#include <hip/hip_runtime.h>

#define BDIM 2
#define SDIM 4096
#define HIDDEN 2048
#define NH 4
#define DD 64
#define RR 32
constexpr float LN_EPS = 1e-5f;

// ---------------------------------------------------------------------------
// Projection kernel: computes q = hs@Wq (+RoPE), k = LN(hs@Wk) (+RoPE), w = hs@Ww
// Grid: (M/64, 6) blocks, 256 threads. N-tile 0..3 = q heads, 4 = k, 5 = w.
// ---------------------------------------------------------------------------
__global__ __launch_bounds__(256) void proj_kernel(
    const float* __restrict__ hs, const float* __restrict__ cosb,
    const float* __restrict__ sinb, const float* __restrict__ Wq,
    const float* __restrict__ Wk, const float* __restrict__ Ww,
    const float* __restrict__ gamma, const float* __restrict__ beta,
    float* __restrict__ qout, float* __restrict__ kout, float* __restrict__ wout)
{
    __shared__ float As[32][68];   // [k][m] transposed A tile
    __shared__ float Bs[32][68];   // [k][n] B tile
    __shared__ float T[64][65];    // output staging tile
    __shared__ float mu_s[64], rs_s[64];

    const int m0  = blockIdx.x * 64;
    const int nt  = blockIdx.y;        // 0..3: q head nt; 4: k; 5: w
    const int tid = threadIdx.x;
    const int tx  = tid & 15, ty = tid >> 4;

    float acc[4][4] = {};

    for (int k0 = 0; k0 < HIDDEN; k0 += 32) {
        // ---- load A tile (64 rows x 32 k), transposed into As[k][m]
        {
            const int row = tid >> 3;          // 0..31
            const int kq  = (tid & 7) * 4;     // 0,4,...,28
            #pragma unroll
            for (int rr = 0; rr < 2; ++rr) {
                const int r = row + rr * 32;
                const float4 v = *reinterpret_cast<const float4*>(
                    &hs[(size_t)(m0 + r) * HIDDEN + k0 + kq]);
                As[kq + 0][r] = v.x; As[kq + 1][r] = v.y;
                As[kq + 2][r] = v.z; As[kq + 3][r] = v.w;
            }
        }
        // ---- load B tile (32 k x 64 n) into Bs[k][n]
        {
            const int kr = tid >> 3;           // 0..31
            const int nq = (tid & 7) * 8;      // 0..56 step 8
            const int gk = k0 + kr;
            if (nt < 4) {
                const float4 v0 = *reinterpret_cast<const float4*>(
                    &Wq[(size_t)gk * 256 + nt * 64 + nq]);
                const float4 v1 = *reinterpret_cast<const float4*>(
                    &Wq[(size_t)gk * 256 + nt * 64 + nq + 4]);
                Bs[kr][nq + 0] = v0.x; Bs[kr][nq + 1] = v0.y;
                Bs[kr][nq + 2] = v0.z; Bs[kr][nq + 3] = v0.w;
                Bs[kr][nq + 4] = v1.x; Bs[kr][nq + 5] = v1.y;
                Bs[kr][nq + 6] = v1.z; Bs[kr][nq + 7] = v1.w;
            } else if (nt == 4) {
                const float4 v0 = *reinterpret_cast<const float4*>(
                    &Wk[(size_t)gk * 64 + nq]);
                const float4 v1 = *reinterpret_cast<const float4*>(
                    &Wk[(size_t)gk * 64 + nq + 4]);
                Bs[kr][nq + 0] = v0.x; Bs[kr][nq + 1] = v0.y;
                Bs[kr][nq + 2] = v0.z; Bs[kr][nq + 3] = v0.w;
                Bs[kr][nq + 4] = v1.x; Bs[kr][nq + 5] = v1.y;
                Bs[kr][nq + 6] = v1.z; Bs[kr][nq + 7] = v1.w;
            } else {
                #pragma unroll
                for (int c = 0; c < 8; ++c) {
                    const int col = nq + c;
                    Bs[kr][col] = (col < NH) ? Ww[(size_t)gk * NH + col] : 0.f;
                }
            }
        }
        __syncthreads();
        // ---- compute
        #pragma unroll 8
        for (int kk = 0; kk < 32; ++kk) {
            const float4 a4 = *reinterpret_cast<const float4*>(&As[kk][ty * 4]);
            const float4 b4 = *reinterpret_cast<const float4*>(&Bs[kk][tx * 4]);
            const float a[4] = {a4.x, a4.y, a4.z, a4.w};
            const float b[4] = {b4.x, b4.y, b4.z, b4.w};
            #pragma unroll
            for (int i = 0; i < 4; ++i)
                #pragma unroll
                for (int j = 0; j < 4; ++j)
                    acc[i][j] = fmaf(a[i], b[j], acc[i][j]);
        }
        __syncthreads();
    }

    // stage to LDS tile
    #pragma unroll
    for (int i = 0; i < 4; ++i)
        #pragma unroll
        for (int j = 0; j < 4; ++j)
            T[ty * 4 + i][tx * 4 + j] = acc[i][j];
    __syncthreads();

    if (nt < 4) {
        // q head nt: RoPE on cols 0..31, write [B,S,H,D]
        const int col = tid & 63;
        const int r0  = tid >> 6;
        #pragma unroll
        for (int it = 0; it < 16; ++it) {
            const int r = r0 + it * 4;
            const int m = m0 + r;      // m = b*S + s
            float val = T[r][col];
            if (col < RR) {
                const float cv = cosb[(size_t)m * RR + col];
                const float sv = sinb[(size_t)m * RR + col];
                const float rot = (col < 16) ? -T[r][col + 16] : T[r][col - 16];
                val = val * cv + rot * sv;
            }
            qout[(size_t)m * (NH * DD) + nt * DD + col] = val;
        }
    } else if (nt == 4) {
        // LayerNorm stats per row
        if (tid < 64) {
            float s = 0.f, s2 = 0.f;
            #pragma unroll 8
            for (int c = 0; c < 64; ++c) { const float v = T[tid][c]; s += v; s2 += v * v; }
            const float mu = s * (1.f / 64.f);
            const float var = s2 * (1.f / 64.f) - mu * mu;
            mu_s[tid] = mu;
            rs_s[tid] = rsqrtf(var + LN_EPS);
        }
        __syncthreads();
        const int col = tid & 63;
        const int r0  = tid >> 6;
        const float g  = gamma[col];
        const float bb = beta[col];
        const int colp = col ^ 16;   // rope partner (only used when col < 32)
        const float gp  = gamma[colp];
        const float bbp = beta[colp];
        #pragma unroll
        for (int it = 0; it < 16; ++it) {
            const int r = r0 + it * 4;
            const int m = m0 + r;
            const float mu = mu_s[r], rs = rs_s[r];
            float kn = (T[r][col] - mu) * rs * g + bb;
            if (col < RR) {
                const float knp = (T[r][colp] - mu) * rs * gp + bbp;
                const float cv = cosb[(size_t)m * RR + col];
                const float sv = sinb[(size_t)m * RR + col];
                const float rot = (col < 16) ? -knp : knp;
                kn = kn * cv + rot * sv;
            }
            kout[(size_t)m * DD + col] = kn;
        }
    } else {
        // w: only cols 0..3 valid
        const int r = tid >> 2;
        const int h = tid & 3;
        wout[(size_t)(m0 + r) * NH + h] = T[r][h];
    }
}

// ---------------------------------------------------------------------------
// Score kernel: out[b,q,k] = sum_h w[b,q,h] * relu(qr[b,q,h,:] . kr[b,k,:])
// Grid: (S/64 k-tiles, S/64 q-tiles, B), 256 threads; 64x64 out tile.
// ---------------------------------------------------------------------------
__global__ __launch_bounds__(256) void score_kernel(
    const float* __restrict__ qr, const float* __restrict__ kr,
    const float* __restrict__ wr, float* __restrict__ out)
{
    __shared__ float Klds[64][68];   // [d][k-row]
    __shared__ float Qlds[64][68];   // [d][q-row]

    const int k0  = blockIdx.x * 64;
    const int q0  = blockIdx.y * 64;
    const int b   = blockIdx.z;
    const int tid = threadIdx.x;
    const int tx  = tid & 15, ty = tid >> 4;

    // load K tile transposed: Klds[d][row]
    {
        const int row = tid >> 2;            // 0..63
        const int dq  = (tid & 3) * 16;
        #pragma unroll
        for (int dd = 0; dd < 4; ++dd) {
            const int d = dq + dd * 4;
            const float4 v = *reinterpret_cast<const float4*>(
                &kr[(size_t)(b * SDIM + k0 + row) * DD + d]);
            Klds[d + 0][row] = v.x; Klds[d + 1][row] = v.y;
            Klds[d + 2][row] = v.z; Klds[d + 3][row] = v.w;
        }
    }

    float outacc[4][4] = {};

    for (int h = 0; h < NH; ++h) {
        __syncthreads();   // K tile ready (h=0); Qlds safe to overwrite (h>0)
        {
            const int row = tid >> 2;
            const int dq  = (tid & 3) * 16;
            #pragma unroll
            for (int dd = 0; dd < 4; ++dd) {
                const int d = dq + dd * 4;
                const float4 v = *reinterpret_cast<const float4*>(
                    &qr[((size_t)(b * SDIM + q0 + row) * NH + h) * DD + d]);
                Qlds[d + 0][row] = v.x; Qlds[d + 1][row] = v.y;
                Qlds[d + 2][row] = v.z; Qlds[d + 3][row] = v.w;
            }
        }
        __syncthreads();

        float s[4][4] = {};
        #pragma unroll 8
        for (int d = 0; d < 64; ++d) {
            const float4 q4 = *reinterpret_cast<const float4*>(&Qlds[d][ty * 4]);
            const float4 k4 = *reinterpret_cast<const float4*>(&Klds[d][tx * 4]);
            const float qa[4] = {q4.x, q4.y, q4.z, q4.w};
            const float ka[4] = {k4.x, k4.y, k4.z, k4.w};
            #pragma unroll
            for (int i = 0; i < 4; ++i)
                #pragma unroll
                for (int j = 0; j < 4; ++j)
                    s[i][j] = fmaf(qa[i], ka[j], s[i][j]);
        }

        float wv[4];
        #pragma unroll
        for (int i = 0; i < 4; ++i)
            wv[i] = wr[(size_t)(b * SDIM + q0 + ty * 4 + i) * NH + h];
        #pragma unroll
        for (int i = 0; i < 4; ++i)
            #pragma unroll
            for (int j = 0; j < 4; ++j)
                outacc[i][j] += wv[i] * fmaxf(s[i][j], 0.f);
    }

    // coalesced float4 out writes
    #pragma unroll
    for (int i = 0; i < 4; ++i) {
        float4 v;
        v.x = outacc[i][0]; v.y = outacc[i][1];
        v.z = outacc[i][2]; v.w = outacc[i][3];
        *reinterpret_cast<float4*>(
            &out[((size_t)b * SDIM + q0 + ty * 4 + i) * SDIM + k0 + tx * 4]) = v;
    }
}

// ---------------------------------------------------------------------------
extern "C" void kernel_launch(void* const* d_in, const int* in_sizes, int n_in,
                              void* d_out, int out_size, void* d_ws, size_t ws_size,
                              hipStream_t stream) {
    const float* hs    = (const float*)d_in[0];
    const float* cosb  = (const float*)d_in[1];
    const float* sinb  = (const float*)d_in[2];
    const float* Wq    = (const float*)d_in[3];
    const float* Wk    = (const float*)d_in[4];
    const float* Ww    = (const float*)d_in[5];
    const float* gamma = (const float*)d_in[6];
    const float* beta  = (const float*)d_in[7];
    float* out = (float*)d_out;

    float* qws = (float*)d_ws;                                   // [B,S,H,D]
    float* kws = qws + (size_t)BDIM * SDIM * NH * DD;            // [B,S,D]
    float* wws = kws + (size_t)BDIM * SDIM * DD;                 // [B,S,H]

    proj_kernel<<<dim3((BDIM * SDIM) / 64, 6), 256, 0, stream>>>(
        hs, cosb, sinb, Wq, Wk, Ww, gamma, beta, qws, kws, wws);

    score_kernel<<<dim3(SDIM / 64, SDIM / 64, BDIM), 256, 0, stream>>>(
        qws, kws, wws, out);
}

// Round 2
// 299.799 us; speedup vs baseline: 1.5199x; 1.5199x over previous
//
#include <hip/hip_runtime.h>

#define BDIM 2
#define SDIM 4096
#define HIDDEN 2048
#define NH 4
#define DD 64
#define RR 32
constexpr float LN_EPS = 1e-5f;

typedef __attribute__((ext_vector_type(8))) short short8;   // 8 bf16 = 4 VGPRs
typedef __attribute__((ext_vector_type(4))) float f32x4;

// round-to-nearest-even f32 -> bf16 (matches HW conversion)
__device__ inline unsigned short f2bf(float f) {
    union { float f; unsigned u; } v; v.f = f;
    unsigned r = v.u + 0x7fff + ((v.u >> 16) & 1);
    return (unsigned short)(r >> 16);
}

// ---------------------------------------------------------------------------
// Projection kernel (fp32 GEMM): q = hs@Wq (+RoPE) -> bf16, k = LN(hs@Wk)
// (+RoPE) -> bf16, w = hs@Ww -> f32.
// Grid: (M/64, 6) blocks, 256 threads. N-tile 0..3 = q heads, 4 = k, 5 = w.
// ---------------------------------------------------------------------------
__global__ __launch_bounds__(256) void proj_kernel(
    const float* __restrict__ hs, const float* __restrict__ cosb,
    const float* __restrict__ sinb, const float* __restrict__ Wq,
    const float* __restrict__ Wk, const float* __restrict__ Ww,
    const float* __restrict__ gamma, const float* __restrict__ beta,
    unsigned short* __restrict__ qout, unsigned short* __restrict__ kout,
    float* __restrict__ wout)
{
    __shared__ float As[32][68];   // [k][m] transposed A tile
    __shared__ float Bs[32][68];   // [k][n] B tile
    __shared__ float T[64][65];    // output staging tile
    __shared__ float mu_s[64], rs_s[64];

    const int m0  = blockIdx.x * 64;
    const int nt  = blockIdx.y;        // 0..3: q head nt; 4: k; 5: w
    const int tid = threadIdx.x;
    const int tx  = tid & 15, ty = tid >> 4;

    float acc[4][4] = {};

    for (int k0 = 0; k0 < HIDDEN; k0 += 32) {
        {
            const int row = tid >> 3;          // 0..31
            const int kq  = (tid & 7) * 4;     // 0,4,...,28
            #pragma unroll
            for (int rr = 0; rr < 2; ++rr) {
                const int r = row + rr * 32;
                const float4 v = *reinterpret_cast<const float4*>(
                    &hs[(size_t)(m0 + r) * HIDDEN + k0 + kq]);
                As[kq + 0][r] = v.x; As[kq + 1][r] = v.y;
                As[kq + 2][r] = v.z; As[kq + 3][r] = v.w;
            }
        }
        {
            const int kr = tid >> 3;           // 0..31
            const int nq = (tid & 7) * 8;      // 0..56 step 8
            const int gk = k0 + kr;
            if (nt < 4) {
                const float4 v0 = *reinterpret_cast<const float4*>(
                    &Wq[(size_t)gk * 256 + nt * 64 + nq]);
                const float4 v1 = *reinterpret_cast<const float4*>(
                    &Wq[(size_t)gk * 256 + nt * 64 + nq + 4]);
                Bs[kr][nq + 0] = v0.x; Bs[kr][nq + 1] = v0.y;
                Bs[kr][nq + 2] = v0.z; Bs[kr][nq + 3] = v0.w;
                Bs[kr][nq + 4] = v1.x; Bs[kr][nq + 5] = v1.y;
                Bs[kr][nq + 6] = v1.z; Bs[kr][nq + 7] = v1.w;
            } else if (nt == 4) {
                const float4 v0 = *reinterpret_cast<const float4*>(
                    &Wk[(size_t)gk * 64 + nq]);
                const float4 v1 = *reinterpret_cast<const float4*>(
                    &Wk[(size_t)gk * 64 + nq + 4]);
                Bs[kr][nq + 0] = v0.x; Bs[kr][nq + 1] = v0.y;
                Bs[kr][nq + 2] = v0.z; Bs[kr][nq + 3] = v0.w;
                Bs[kr][nq + 4] = v1.x; Bs[kr][nq + 5] = v1.y;
                Bs[kr][nq + 6] = v1.z; Bs[kr][nq + 7] = v1.w;
            } else {
                #pragma unroll
                for (int c = 0; c < 8; ++c) {
                    const int col = nq + c;
                    Bs[kr][col] = (col < NH) ? Ww[(size_t)gk * NH + col] : 0.f;
                }
            }
        }
        __syncthreads();
        #pragma unroll 8
        for (int kk = 0; kk < 32; ++kk) {
            const float4 a4 = *reinterpret_cast<const float4*>(&As[kk][ty * 4]);
            const float4 b4 = *reinterpret_cast<const float4*>(&Bs[kk][tx * 4]);
            const float a[4] = {a4.x, a4.y, a4.z, a4.w};
            const float b[4] = {b4.x, b4.y, b4.z, b4.w};
            #pragma unroll
            for (int i = 0; i < 4; ++i)
                #pragma unroll
                for (int j = 0; j < 4; ++j)
                    acc[i][j] = fmaf(a[i], b[j], acc[i][j]);
        }
        __syncthreads();
    }

    #pragma unroll
    for (int i = 0; i < 4; ++i)
        #pragma unroll
        for (int j = 0; j < 4; ++j)
            T[ty * 4 + i][tx * 4 + j] = acc[i][j];
    __syncthreads();

    if (nt < 4) {
        const int col = tid & 63;
        const int r0  = tid >> 6;
        #pragma unroll
        for (int it = 0; it < 16; ++it) {
            const int r = r0 + it * 4;
            const int m = m0 + r;      // m = b*S + s
            float val = T[r][col];
            if (col < RR) {
                const float cv = cosb[(size_t)m * RR + col];
                const float sv = sinb[(size_t)m * RR + col];
                const float rot = (col < 16) ? -T[r][col + 16] : T[r][col - 16];
                val = val * cv + rot * sv;
            }
            qout[(size_t)m * (NH * DD) + nt * DD + col] = f2bf(val);
        }
    } else if (nt == 4) {
        if (tid < 64) {
            float s = 0.f, s2 = 0.f;
            #pragma unroll 8
            for (int c = 0; c < 64; ++c) { const float v = T[tid][c]; s += v; s2 += v * v; }
            const float mu = s * (1.f / 64.f);
            const float var = s2 * (1.f / 64.f) - mu * mu;
            mu_s[tid] = mu;
            rs_s[tid] = rsqrtf(var + LN_EPS);
        }
        __syncthreads();
        const int col = tid & 63;
        const int r0  = tid >> 6;
        const float g  = gamma[col];
        const float bb = beta[col];
        const int colp = col ^ 16;
        const float gp  = gamma[colp];
        const float bbp = beta[colp];
        #pragma unroll
        for (int it = 0; it < 16; ++it) {
            const int r = r0 + it * 4;
            const int m = m0 + r;
            const float mu = mu_s[r], rs = rs_s[r];
            float kn = (T[r][col] - mu) * rs * g + bb;
            if (col < RR) {
                const float knp = (T[r][colp] - mu) * rs * gp + bbp;
                const float cv = cosb[(size_t)m * RR + col];
                const float sv = sinb[(size_t)m * RR + col];
                const float rot = (col < 16) ? -knp : knp;
                kn = kn * cv + rot * sv;
            }
            kout[(size_t)m * DD + col] = f2bf(kn);
        }
    } else {
        const int r = tid >> 2;
        const int h = tid & 3;
        wout[(size_t)(m0 + r) * NH + h] = T[r][h];
    }
}

// ---------------------------------------------------------------------------
// Score kernel (bf16 MFMA): out[b,q,k] = sum_h w[b,q,h]*relu(q[b,q,h,:].k[b,k,:])
// Grid: (S/64 k, S/64 q, B), 256 threads = 4 waves; each wave a 32x32 quadrant.
// No LDS: fragments loaded straight from L2-resident q/k workspace.
// Fragment layout (mfma_f32_16x16x32_bf16):
//   A/B: lane holds row/col (lane&15), d = (lane>>4)*8 + j
//   C/D: col = lane&15, row = (lane>>4)*4 + reg
// ---------------------------------------------------------------------------
__global__ __launch_bounds__(256) void score_kernel(
    const unsigned short* __restrict__ qb, const unsigned short* __restrict__ kb,
    const float* __restrict__ wr, float* __restrict__ out)
{
    const int k0   = blockIdx.x * 64;
    const int q0   = blockIdx.y * 64;
    const int b    = blockIdx.z;
    const int tid  = threadIdx.x;
    const int wave = tid >> 6;
    const int lane = tid & 63;
    const int wm = wave >> 1, wn = wave & 1;
    const int lrow = lane & 15;
    const int ld8  = (lane >> 4) * 8;
    const int lr4  = (lane >> 4) * 4;

    const int qrow0 = q0 + wm * 32;
    const int krow0 = k0 + wn * 32;

    // K fragments (h-invariant): bf[j][ks], j = 16-col strip, ks = 32-wide k step
    short8 bf[2][2];
    #pragma unroll
    for (int j = 0; j < 2; ++j)
        #pragma unroll
        for (int ks = 0; ks < 2; ++ks)
            bf[j][ks] = *reinterpret_cast<const short8*>(
                &kb[(size_t)(b * SDIM + krow0 + j * 16 + lrow) * DD + ks * 32 + ld8]);

    f32x4 zero4 = {0.f, 0.f, 0.f, 0.f};
    f32x4 oacc[2][2];
    #pragma unroll
    for (int i = 0; i < 2; ++i)
        #pragma unroll
        for (int j = 0; j < 2; ++j)
            oacc[i][j] = zero4;

    for (int h = 0; h < NH; ++h) {
        short8 af[2][2];
        #pragma unroll
        for (int i = 0; i < 2; ++i)
            #pragma unroll
            for (int ks = 0; ks < 2; ++ks)
                af[i][ks] = *reinterpret_cast<const short8*>(
                    &qb[((size_t)(b * SDIM + qrow0 + i * 16 + lrow) * NH + h) * DD
                        + ks * 32 + ld8]);

        f32x4 s[2][2];
        #pragma unroll
        for (int i = 0; i < 2; ++i)
            #pragma unroll
            for (int j = 0; j < 2; ++j)
                s[i][j] = zero4;

        #pragma unroll
        for (int ks = 0; ks < 2; ++ks)
            #pragma unroll
            for (int i = 0; i < 2; ++i)
                #pragma unroll
                for (int j = 0; j < 2; ++j)
                    s[i][j] = __builtin_amdgcn_mfma_f32_16x16x32_bf16(
                        af[i][ks], bf[j][ks], s[i][j], 0, 0, 0);

        #pragma unroll
        for (int i = 0; i < 2; ++i) {
            #pragma unroll
            for (int r = 0; r < 4; ++r) {
                const float wv = wr[(size_t)(b * SDIM + qrow0 + i * 16 + lr4 + r) * NH + h];
                #pragma unroll
                for (int j = 0; j < 2; ++j)
                    oacc[i][j][r] += wv * fmaxf(s[i][j][r], 0.f);
            }
        }
    }

    #pragma unroll
    for (int i = 0; i < 2; ++i)
        #pragma unroll
        for (int r = 0; r < 4; ++r)
            #pragma unroll
            for (int j = 0; j < 2; ++j)
                out[(size_t)(b * SDIM + qrow0 + i * 16 + lr4 + r) * SDIM
                    + krow0 + j * 16 + lrow] = oacc[i][j][r];
}

// ---------------------------------------------------------------------------
extern "C" void kernel_launch(void* const* d_in, const int* in_sizes, int n_in,
                              void* d_out, int out_size, void* d_ws, size_t ws_size,
                              hipStream_t stream) {
    const float* hs    = (const float*)d_in[0];
    const float* cosb  = (const float*)d_in[1];
    const float* sinb  = (const float*)d_in[2];
    const float* Wq    = (const float*)d_in[3];
    const float* Wk    = (const float*)d_in[4];
    const float* Ww    = (const float*)d_in[5];
    const float* gamma = (const float*)d_in[6];
    const float* beta  = (const float*)d_in[7];
    float* out = (float*)d_out;

    char* wsb = (char*)d_ws;
    unsigned short* qb = (unsigned short*)wsb;                       // [B,S,H,D] bf16
    unsigned short* kb = (unsigned short*)(wsb + (size_t)BDIM * SDIM * NH * DD * 2);
    float*          ww = (float*)(wsb + (size_t)BDIM * SDIM * NH * DD * 2
                                      + (size_t)BDIM * SDIM * DD * 2);

    proj_kernel<<<dim3((BDIM * SDIM) / 64, 6), 256, 0, stream>>>(
        hs, cosb, sinb, Wq, Wk, Ww, gamma, beta, qb, kb, ww);

    score_kernel<<<dim3(SDIM / 64, SDIM / 64, BDIM), 256, 0, stream>>>(
        qb, kb, ww, out);
}

// Round 3
// 177.593 us; speedup vs baseline: 2.5658x; 1.6881x over previous
//
#include <hip/hip_runtime.h>

#define BDIM 2
#define SDIM 4096
#define HIDDEN 2048
#define NH 4
#define DD 64
#define RR 32
constexpr float LN_EPS = 1e-5f;

typedef __attribute__((ext_vector_type(8))) short short8;   // 8 bf16 = 4 VGPRs
typedef __attribute__((ext_vector_type(4))) short short4v;  // 4 bf16 = 2 VGPRs
typedef __attribute__((ext_vector_type(4))) float f32x4;

// round-to-nearest-even f32 -> bf16
__device__ inline unsigned short f2bf(float f) {
    union { float f; unsigned u; } v; v.f = f;
    unsigned r = v.u + 0x7fff + ((v.u >> 16) & 1);
    return (unsigned short)(r >> 16);
}
__device__ inline float bf2f(unsigned short u) {
    union { unsigned u; float f; } v; v.u = ((unsigned)u) << 16;
    return v.f;
}

// LDS XOR swizzle: breaks the 128B-row-stride bank conflict (G4/T2).
// Must be applied identically on write and read.
#define SWZ(row, kbyte) ((((row) * 128) + (kbyte)) ^ (((row) & 7) << 4))

// ---------------------------------------------------------------------------
// Prep: Wt[n][k] bf16, n-order: q cols 0..255 (head=n>>6,d=n&63), k cols
// 256..319, w cols 320..323, zeros 324..383. Transposed, k-contiguous.
// Grid: (2048/64, 384/64), 256 threads.
// ---------------------------------------------------------------------------
__global__ __launch_bounds__(256) void prep_w(
    const float* __restrict__ Wq, const float* __restrict__ Wk,
    const float* __restrict__ Ww, unsigned short* __restrict__ Wt)
{
    __shared__ float T[64][65];
    const int k0 = blockIdx.x * 64, n0 = blockIdx.y * 64;
    const int tid = threadIdx.x;
    {
        const int kr = tid >> 2;
        const int nq = (tid & 3) * 16;
        const int gk = k0 + kr;
        #pragma unroll
        for (int c = 0; c < 16; ++c) {
            const int n = n0 + nq + c;
            float v;
            if (n < 256)      v = Wq[(size_t)gk * 256 + n];
            else if (n < 320) v = Wk[(size_t)gk * 64 + (n - 256)];
            else if (n < 324) v = Ww[(size_t)gk * NH + (n - 320)];
            else              v = 0.f;
            T[kr][nq + c] = v;
        }
    }
    __syncthreads();
    {
        const int nr = tid >> 2;
        const int kc = (tid & 3) * 16;
        unsigned short tmp[16];
        #pragma unroll
        for (int c = 0; c < 16; ++c) tmp[c] = f2bf(T[kc + c][nr]);
        *reinterpret_cast<short8*>(&Wt[(size_t)(n0 + nr) * HIDDEN + k0 + kc]) =
            *reinterpret_cast<short8*>(&tmp[0]);
        *reinterpret_cast<short8*>(&Wt[(size_t)(n0 + nr) * HIDDEN + k0 + kc + 8]) =
            *reinterpret_cast<short8*>(&tmp[8]);
    }
}

// ---------------------------------------------------------------------------
// Proj (bf16 MFMA, hs split hi+lo): 64M x 64N per block, BK=64, 4 waves 2x2,
// wave tile 32x32 (2x2 frags of 16x16x32). n-group: 0..3 q heads, 4 k, 5 w.
// ---------------------------------------------------------------------------
__global__ __launch_bounds__(256) void proj_mfma(
    const float* __restrict__ hs, const unsigned short* __restrict__ Wt,
    const float* __restrict__ cosb, const float* __restrict__ sinb,
    const float* __restrict__ gamma, const float* __restrict__ beta,
    unsigned short* __restrict__ qout, unsigned short* __restrict__ kout,
    float* __restrict__ wout)
{
    __shared__ unsigned short Ah[64 * 64];   // swizzled [row][64k] bf16, 8KB
    __shared__ unsigned short Al[64 * 64];
    __shared__ unsigned short Bt[64 * 64];
    __shared__ float LNs1[2][64], LNs2[2][64];

    const int m0  = blockIdx.x * 64;
    const int ng  = blockIdx.y;
    const int tid = threadIdx.x;
    const int wave = tid >> 6, lane = tid & 63;
    const int wm = wave >> 1, wn = wave & 1;
    const int lr = lane & 15, lh = lane >> 4;

    const int arow = tid >> 4;        // 0..15, +16p
    const int akq  = (tid & 15) * 4;  // k elem for A stage
    const int brow = tid >> 2;        // 0..63
    const int bkq  = (tid & 3) * 8;   // k elem for B stage (+32c)

    f32x4 acc[2][2];
    #pragma unroll
    for (int i = 0; i < 2; ++i)
        #pragma unroll
        for (int j = 0; j < 2; ++j)
            acc[i][j] = (f32x4){0.f, 0.f, 0.f, 0.f};

    for (int k0 = 0; k0 < HIDDEN; k0 += 64) {
        // ---- stage A (fp32 -> hi/lo bf16, swizzled)
        #pragma unroll
        for (int p = 0; p < 4; ++p) {
            const int row = arow + p * 16;
            const float4 v = *reinterpret_cast<const float4*>(
                &hs[(size_t)(m0 + row) * HIDDEN + k0 + akq]);
            unsigned short h[4], l[4];
            h[0] = f2bf(v.x); l[0] = f2bf(v.x - bf2f(h[0]));
            h[1] = f2bf(v.y); l[1] = f2bf(v.y - bf2f(h[1]));
            h[2] = f2bf(v.z); l[2] = f2bf(v.z - bf2f(h[2]));
            h[3] = f2bf(v.w); l[3] = f2bf(v.w - bf2f(h[3]));
            const int off = SWZ(row, akq * 2);
            *reinterpret_cast<short4v*>((char*)Ah + off) =
                *reinterpret_cast<short4v*>(&h[0]);
            *reinterpret_cast<short4v*>((char*)Al + off) =
                *reinterpret_cast<short4v*>(&l[0]);
        }
        // ---- stage B (bf16 copy, swizzled)
        #pragma unroll
        for (int c = 0; c < 2; ++c) {
            const int ke = bkq + c * 32;
            const short8 w8 = *reinterpret_cast<const short8*>(
                &Wt[(size_t)(ng * 64 + brow) * HIDDEN + k0 + ke]);
            *reinterpret_cast<short8*>((char*)Bt + SWZ(brow, ke * 2)) = w8;
        }
        __syncthreads();
        // ---- compute
        #pragma unroll
        for (int kk = 0; kk < 2; ++kk) {
            short8 ah[2], al[2], bb[2];
            #pragma unroll
            for (int i = 0; i < 2; ++i) {
                const int row = wm * 32 + i * 16 + lr;
                const int off = SWZ(row, kk * 64 + lh * 16);
                ah[i] = *reinterpret_cast<const short8*>((const char*)Ah + off);
                al[i] = *reinterpret_cast<const short8*>((const char*)Al + off);
            }
            #pragma unroll
            for (int j = 0; j < 2; ++j) {
                const int row = wn * 32 + j * 16 + lr;
                const int off = SWZ(row, kk * 64 + lh * 16);
                bb[j] = *reinterpret_cast<const short8*>((const char*)Bt + off);
            }
            #pragma unroll
            for (int i = 0; i < 2; ++i)
                #pragma unroll
                for (int j = 0; j < 2; ++j) {
                    acc[i][j] = __builtin_amdgcn_mfma_f32_16x16x32_bf16(
                        ah[i], bb[j], acc[i][j], 0, 0, 0);
                    acc[i][j] = __builtin_amdgcn_mfma_f32_16x16x32_bf16(
                        al[i], bb[j], acc[i][j], 0, 0, 0);
                }
        }
        __syncthreads();
    }

    // ---- epilogue. C/D layout: col = lr (n), row = lh*4+r (m).
    if (ng < 4) {
        // q head ng: d = wn*32 + j*16 + lr; RoPE pairs j0/j1 when wn==0
        #pragma unroll
        for (int i = 0; i < 2; ++i)
            #pragma unroll
            for (int r = 0; r < 4; ++r) {
                const int m = m0 + wm * 32 + i * 16 + lh * 4 + r;
                float x0 = acc[i][0][r], x1 = acc[i][1][r];
                if (wn == 0) {
                    const int d0 = lr, d1 = 16 + lr;
                    const float c0 = cosb[(size_t)m * RR + d0];
                    const float s0 = sinb[(size_t)m * RR + d0];
                    const float c1 = cosb[(size_t)m * RR + d1];
                    const float s1 = sinb[(size_t)m * RR + d1];
                    const float n0 = x0 * c0 - x1 * s0;
                    const float n1 = x1 * c1 + x0 * s1;
                    x0 = n0; x1 = n1;
                }
                const size_t base = (size_t)m * (NH * DD) + ng * DD + wn * 32 + lr;
                qout[base]      = f2bf(x0);
                qout[base + 16] = f2bf(x1);
            }
    } else if (ng == 4) {
        // k: LayerNorm over d=0..63 (cross-wave via LDS partials), then RoPE
        #pragma unroll
        for (int i = 0; i < 2; ++i)
            #pragma unroll
            for (int r = 0; r < 4; ++r) {
                float t1 = acc[i][0][r] + acc[i][1][r];
                float t2 = acc[i][0][r] * acc[i][0][r]
                         + acc[i][1][r] * acc[i][1][r];
                #pragma unroll
                for (int msk = 1; msk < 16; msk <<= 1) {
                    t1 += __shfl_xor(t1, msk, 64);
                    t2 += __shfl_xor(t2, msk, 64);
                }
                if (lr == 0) {
                    const int row = wm * 32 + i * 16 + lh * 4 + r;
                    LNs1[wn][row] = t1;
                    LNs2[wn][row] = t2;
                }
            }
        __syncthreads();
        const float g0 = gamma[wn * 32 + lr],      b0 = beta[wn * 32 + lr];
        const float g1 = gamma[wn * 32 + 16 + lr], b1 = beta[wn * 32 + 16 + lr];
        #pragma unroll
        for (int i = 0; i < 2; ++i)
            #pragma unroll
            for (int r = 0; r < 4; ++r) {
                const int row = wm * 32 + i * 16 + lh * 4 + r;
                const int m = m0 + row;
                const float S1 = LNs1[0][row] + LNs1[1][row];
                const float S2 = LNs2[0][row] + LNs2[1][row];
                const float mu = S1 * (1.f / 64.f);
                const float var = S2 * (1.f / 64.f) - mu * mu;
                const float rs = rsqrtf(var + LN_EPS);
                float x0 = (acc[i][0][r] - mu) * rs * g0 + b0;
                float x1 = (acc[i][1][r] - mu) * rs * g1 + b1;
                if (wn == 0) {
                    const int d0 = lr, d1 = 16 + lr;
                    const float c0 = cosb[(size_t)m * RR + d0];
                    const float s0 = sinb[(size_t)m * RR + d0];
                    const float c1 = cosb[(size_t)m * RR + d1];
                    const float s1 = sinb[(size_t)m * RR + d1];
                    const float n0 = x0 * c0 - x1 * s0;
                    const float n1 = x1 * c1 + x0 * s1;
                    x0 = n0; x1 = n1;
                }
                const size_t base = (size_t)m * DD + wn * 32 + lr;
                kout[base]      = f2bf(x0);
                kout[base + 16] = f2bf(x1);
            }
    } else {
        // w: cols 320..323 -> wn==0, j==0, lr<4
        if (wn == 0 && lr < NH) {
            #pragma unroll
            for (int i = 0; i < 2; ++i)
                #pragma unroll
                for (int r = 0; r < 4; ++r) {
                    const int m = m0 + wm * 32 + i * 16 + lh * 4 + r;
                    wout[(size_t)m * NH + lr] = acc[i][0][r];
                }
        }
    }
}

// ---------------------------------------------------------------------------
// Score kernel (unchanged from R2): bf16 MFMA, no LDS, 4 waves per 64x64 tile.
// ---------------------------------------------------------------------------
__global__ __launch_bounds__(256) void score_kernel(
    const unsigned short* __restrict__ qb, const unsigned short* __restrict__ kb,
    const float* __restrict__ wr, float* __restrict__ out)
{
    const int k0   = blockIdx.x * 64;
    const int q0   = blockIdx.y * 64;
    const int b    = blockIdx.z;
    const int tid  = threadIdx.x;
    const int wave = tid >> 6;
    const int lane = tid & 63;
    const int wm = wave >> 1, wn = wave & 1;
    const int lrow = lane & 15;
    const int ld8  = (lane >> 4) * 8;
    const int lr4  = (lane >> 4) * 4;

    const int qrow0 = q0 + wm * 32;
    const int krow0 = k0 + wn * 32;

    short8 bf[2][2];
    #pragma unroll
    for (int j = 0; j < 2; ++j)
        #pragma unroll
        for (int ks = 0; ks < 2; ++ks)
            bf[j][ks] = *reinterpret_cast<const short8*>(
                &kb[(size_t)(b * SDIM + krow0 + j * 16 + lrow) * DD + ks * 32 + ld8]);

    f32x4 zero4 = {0.f, 0.f, 0.f, 0.f};
    f32x4 oacc[2][2];
    #pragma unroll
    for (int i = 0; i < 2; ++i)
        #pragma unroll
        for (int j = 0; j < 2; ++j)
            oacc[i][j] = zero4;

    for (int h = 0; h < NH; ++h) {
        short8 af[2][2];
        #pragma unroll
        for (int i = 0; i < 2; ++i)
            #pragma unroll
            for (int ks = 0; ks < 2; ++ks)
                af[i][ks] = *reinterpret_cast<const short8*>(
                    &qb[((size_t)(b * SDIM + qrow0 + i * 16 + lrow) * NH + h) * DD
                        + ks * 32 + ld8]);

        f32x4 s[2][2];
        #pragma unroll
        for (int i = 0; i < 2; ++i)
            #pragma unroll
            for (int j = 0; j < 2; ++j)
                s[i][j] = zero4;

        #pragma unroll
        for (int ks = 0; ks < 2; ++ks)
            #pragma unroll
            for (int i = 0; i < 2; ++i)
                #pragma unroll
                for (int j = 0; j < 2; ++j)
                    s[i][j] = __builtin_amdgcn_mfma_f32_16x16x32_bf16(
                        af[i][ks], bf[j][ks], s[i][j], 0, 0, 0);

        #pragma unroll
        for (int i = 0; i < 2; ++i) {
            #pragma unroll
            for (int r = 0; r < 4; ++r) {
                const float wv = wr[(size_t)(b * SDIM + qrow0 + i * 16 + lr4 + r) * NH + h];
                #pragma unroll
                for (int j = 0; j < 2; ++j)
                    oacc[i][j][r] += wv * fmaxf(s[i][j][r], 0.f);
            }
        }
    }

    #pragma unroll
    for (int i = 0; i < 2; ++i)
        #pragma unroll
        for (int r = 0; r < 4; ++r)
            #pragma unroll
            for (int j = 0; j < 2; ++j)
                out[(size_t)(b * SDIM + qrow0 + i * 16 + lr4 + r) * SDIM
                    + krow0 + j * 16 + lrow] = oacc[i][j][r];
}

// ---------------------------------------------------------------------------
extern "C" void kernel_launch(void* const* d_in, const int* in_sizes, int n_in,
                              void* d_out, int out_size, void* d_ws, size_t ws_size,
                              hipStream_t stream) {
    const float* hs    = (const float*)d_in[0];
    const float* cosb  = (const float*)d_in[1];
    const float* sinb  = (const float*)d_in[2];
    const float* Wq    = (const float*)d_in[3];
    const float* Wk    = (const float*)d_in[4];
    const float* Ww    = (const float*)d_in[5];
    const float* gamma = (const float*)d_in[6];
    const float* beta  = (const float*)d_in[7];
    float* out = (float*)d_out;

    char* wsb = (char*)d_ws;
    unsigned short* qb = (unsigned short*)wsb;                                 // [B*S,256] bf16
    unsigned short* kb = (unsigned short*)(wsb + (size_t)BDIM * SDIM * 256 * 2);
    float*          ww = (float*)(wsb + (size_t)BDIM * SDIM * 256 * 2
                                       + (size_t)BDIM * SDIM * DD * 2);
    unsigned short* Wt = (unsigned short*)(wsb + (size_t)BDIM * SDIM * 256 * 2
                                                + (size_t)BDIM * SDIM * DD * 2
                                                + (size_t)BDIM * SDIM * NH * 4);

    prep_w<<<dim3(HIDDEN / 64, 384 / 64), 256, 0, stream>>>(Wq, Wk, Ww, Wt);

    proj_mfma<<<dim3((BDIM * SDIM) / 64, 6), 256, 0, stream>>>(
        hs, Wt, cosb, sinb, gamma, beta, qb, kb, ww);

    score_kernel<<<dim3(SDIM / 64, SDIM / 64, BDIM), 256, 0, stream>>>(
        qb, kb, ww, out);
}

// Round 4
// 164.750 us; speedup vs baseline: 2.7658x; 1.0780x over previous
//
#include <hip/hip_runtime.h>

#define BDIM 2
#define SDIM 4096
#define HIDDEN 2048
#define K2 4096          // split K: (hi,lo) interleaved
#define NH 4
#define DD 64
#define RR 32
constexpr float LN_EPS = 1e-5f;

typedef __attribute__((ext_vector_type(8))) short short8;   // 8 bf16 = 4 VGPRs
typedef __attribute__((ext_vector_type(4))) float f32x4;

// round-to-nearest-even f32 -> bf16
__device__ inline unsigned short f2bf(float f) {
    union { float f; unsigned u; } v; v.f = f;
    unsigned r = v.u + 0x7fff + ((v.u >> 16) & 1);
    return (unsigned short)(r >> 16);
}
__device__ inline float bf2f(unsigned short u) {
    union { unsigned u; float f; } v; v.u = ((unsigned)u) << 16;
    return v.f;
}

// async global -> LDS, 16 B per lane (wave-uniform LDS base + lane*16)
__device__ __forceinline__ void gload_lds16(const unsigned short* g, unsigned short* l) {
    __builtin_amdgcn_global_load_lds(
        (const __attribute__((address_space(1))) void*)g,
        (__attribute__((address_space(3))) void*)l, 16, 0, 0);
}

// ---------------------------------------------------------------------------
// split_hs: hs f32 [M,2048] -> hs2 bf16 [M,4096], (hi,lo) pairs along K,
// PRE-SWIZZLED within each row: elem_off ^= (m&7)<<3 (16B-slot XOR) so that
// linear global_load_lds staging + XOR'd ds_read is conflict-free (rule #21).
// One thread per 16B slot (4 f32 -> 8 bf16). Grid 16384 x 256 exact.
// ---------------------------------------------------------------------------
__global__ __launch_bounds__(256) void split_hs(
    const float* __restrict__ hs, unsigned short* __restrict__ hs2)
{
    const int idx  = blockIdx.x * 256 + threadIdx.x;
    const int m    = idx >> 9;          // 512 slots per row
    const int slot = idx & 511;
    const float4 v = *reinterpret_cast<const float4*>(&hs[(size_t)m * HIDDEN + slot * 4]);
    unsigned short o[8];
    o[0] = f2bf(v.x); o[1] = f2bf(v.x - bf2f(o[0]));
    o[2] = f2bf(v.y); o[3] = f2bf(v.y - bf2f(o[2]));
    o[4] = f2bf(v.z); o[5] = f2bf(v.z - bf2f(o[4]));
    o[6] = f2bf(v.w); o[7] = f2bf(v.w - bf2f(o[6]));
    const int eoff = (slot * 8) ^ ((m & 7) << 3);
    *reinterpret_cast<short8*>(&hs2[(size_t)m * K2 + eoff]) =
        *reinterpret_cast<short8*>(o);
}

// ---------------------------------------------------------------------------
// prep_w2: Wt2 bf16 [384][4096], each source W[k][n] duplicated at k2=2k,2k+1
// (matches hs2's (hi,lo) pairing), pre-swizzled like hs2. n-order: q 0..255,
// k 256..319, w 320..323, zeros to 383. Grid (2048/64, 384/64), 256 thr.
// ---------------------------------------------------------------------------
__global__ __launch_bounds__(256) void prep_w2(
    const float* __restrict__ Wq, const float* __restrict__ Wk,
    const float* __restrict__ Ww, unsigned short* __restrict__ Wt2)
{
    __shared__ float T[64][65];
    const int k0 = blockIdx.x * 64, n0 = blockIdx.y * 64;
    const int tid = threadIdx.x;
    {
        const int kr = tid >> 2;
        const int nq = (tid & 3) * 16;
        const int gk = k0 + kr;
        #pragma unroll
        for (int c = 0; c < 16; ++c) {
            const int n = n0 + nq + c;
            float v;
            if (n < 256)      v = Wq[(size_t)gk * 256 + n];
            else if (n < 320) v = Wk[(size_t)gk * 64 + (n - 256)];
            else if (n < 324) v = Ww[(size_t)gk * NH + (n - 320)];
            else              v = 0.f;
            T[kr][nq + c] = v;
        }
    }
    __syncthreads();
    {
        const int nr = tid >> 2;
        const int kc = (tid & 3) * 16;
        const int n  = n0 + nr;
        #pragma unroll
        for (int s = 0; s < 4; ++s) {
            const int kb = kc + s * 4;
            unsigned short e[8];
            #pragma unroll
            for (int t = 0; t < 4; ++t) {
                const unsigned short b = f2bf(T[kb + t][nr]);
                e[2 * t] = b; e[2 * t + 1] = b;
            }
            const int eoff = (2 * (k0 + kb)) ^ ((nr & 7) << 3);
            *reinterpret_cast<short8*>(&Wt2[(size_t)n * K2 + eoff]) =
                *reinterpret_cast<short8*>(e);
        }
    }
}

// ---------------------------------------------------------------------------
// proj_mfma v2 (m97 structure): 128M x 64N tile, BK=128, grid (64,6),
// 4 waves each owning 32M x 64N (acc[2][4]). global_load_lds staging (linear
// LDS dest, pre-swizzled global source), XOR'd ds_read_b128 fragments.
// Epilogue: ng 0..3 q+RoPE, 4 k LN+RoPE (intra-wave shfl), 5 w.
// ---------------------------------------------------------------------------
__global__ __launch_bounds__(256) void proj_mfma(
    const unsigned short* __restrict__ hs2, const unsigned short* __restrict__ Wt2,
    const float* __restrict__ cosb, const float* __restrict__ sinb,
    const float* __restrict__ gamma, const float* __restrict__ beta,
    unsigned short* __restrict__ qout, unsigned short* __restrict__ kout,
    float* __restrict__ wout)
{
    __shared__ unsigned short Asm[128 * 128];   // 32 KB: [row][128 elems]
    __shared__ unsigned short Bsm[64 * 128];    // 16 KB

    const int m0   = blockIdx.x * 128;
    const int ng   = blockIdx.y;
    const int tid  = threadIdx.x;
    const int wave = tid >> 6, lane = tid & 63;
    const int lr = lane & 15, lh = lane >> 4;

    f32x4 acc[2][4];
    #pragma unroll
    for (int i = 0; i < 2; ++i)
        #pragma unroll
        for (int j = 0; j < 4; ++j)
            acc[i][j] = (f32x4){0.f, 0.f, 0.f, 0.f};

    // staging: thread t covers row (i*16 + t>>4), 16B slot (t&15)
    const int srow  = tid >> 4;
    const int sslot = tid & 15;
    const unsigned short* gA = hs2 + (size_t)(m0 + srow) * K2 + sslot * 8;
    const unsigned short* gB = Wt2 + (size_t)(ng * 64 + srow) * K2 + sslot * 8;
    unsigned short* lA = Asm + tid * 8;   // + issue*2048 elems (= 16 rows)
    unsigned short* lB = Bsm + tid * 8;

    for (int k0 = 0; k0 < K2; k0 += 128) {
        #pragma unroll
        for (int i = 0; i < 8; ++i)
            gload_lds16(gA + (size_t)i * 16 * K2 + k0, lA + i * 2048);
        #pragma unroll
        for (int i = 0; i < 4; ++i)
            gload_lds16(gB + (size_t)i * 16 * K2 + k0, lB + i * 2048);
        __syncthreads();

        #pragma unroll
        for (int kk = 0; kk < 4; ++kk) {
            short8 av[2], bv[4];
            #pragma unroll
            for (int i = 0; i < 2; ++i) {
                const int row = wave * 32 + i * 16 + lr;
                const int off = (row * 128 + kk * 32 + lh * 8) ^ ((row & 7) << 3);
                av[i] = *reinterpret_cast<const short8*>(&Asm[off]);
            }
            #pragma unroll
            for (int j = 0; j < 4; ++j) {
                const int row = j * 16 + lr;
                const int off = (row * 128 + kk * 32 + lh * 8) ^ ((row & 7) << 3);
                bv[j] = *reinterpret_cast<const short8*>(&Bsm[off]);
            }
            #pragma unroll
            for (int i = 0; i < 2; ++i)
                #pragma unroll
                for (int j = 0; j < 4; ++j)
                    acc[i][j] = __builtin_amdgcn_mfma_f32_16x16x32_bf16(
                        av[i], bv[j], acc[i][j], 0, 0, 0);
        }
        __syncthreads();
    }

    // ---- epilogue. C/D: col = lr + j*16, row = wave*32 + i*16 + lh*4 + r
    if (ng < 4) {
        #pragma unroll
        for (int i = 0; i < 2; ++i)
            #pragma unroll
            for (int r = 0; r < 4; ++r) {
                const int m = m0 + wave * 32 + i * 16 + lh * 4 + r;
                const float x0 = acc[i][0][r], x1 = acc[i][1][r];
                const float c0 = cosb[(size_t)m * RR + lr];
                const float s0 = sinb[(size_t)m * RR + lr];
                const float c1 = cosb[(size_t)m * RR + 16 + lr];
                const float s1 = sinb[(size_t)m * RR + 16 + lr];
                const size_t base = (size_t)m * (NH * DD) + ng * DD + lr;
                qout[base]      = f2bf(x0 * c0 - x1 * s0);
                qout[base + 16] = f2bf(x1 * c1 + x0 * s1);
                qout[base + 32] = f2bf(acc[i][2][r]);
                qout[base + 48] = f2bf(acc[i][3][r]);
            }
    } else if (ng == 4) {
        float g[4], bb[4];
        #pragma unroll
        for (int j = 0; j < 4; ++j) { g[j] = gamma[j * 16 + lr]; bb[j] = beta[j * 16 + lr]; }
        #pragma unroll
        for (int i = 0; i < 2; ++i)
            #pragma unroll
            for (int r = 0; r < 4; ++r) {
                float t1 = 0.f, t2 = 0.f;
                #pragma unroll
                for (int j = 0; j < 4; ++j) {
                    const float a = acc[i][j][r];
                    t1 += a; t2 += a * a;
                }
                #pragma unroll
                for (int msk = 1; msk < 16; msk <<= 1) {
                    t1 += __shfl_xor(t1, msk, 64);
                    t2 += __shfl_xor(t2, msk, 64);
                }
                const float mu  = t1 * (1.f / 64.f);
                const float var = t2 * (1.f / 64.f) - mu * mu;
                const float rs  = rsqrtf(var + LN_EPS);
                const int m = m0 + wave * 32 + i * 16 + lh * 4 + r;
                float x[4];
                #pragma unroll
                for (int j = 0; j < 4; ++j)
                    x[j] = (acc[i][j][r] - mu) * rs * g[j] + bb[j];
                const float c0 = cosb[(size_t)m * RR + lr];
                const float s0 = sinb[(size_t)m * RR + lr];
                const float c1 = cosb[(size_t)m * RR + 16 + lr];
                const float s1 = sinb[(size_t)m * RR + 16 + lr];
                const float n0 = x[0] * c0 - x[1] * s0;
                const float n1 = x[1] * c1 + x[0] * s1;
                const size_t base = (size_t)m * DD + lr;
                kout[base]      = f2bf(n0);
                kout[base + 16] = f2bf(n1);
                kout[base + 32] = f2bf(x[2]);
                kout[base + 48] = f2bf(x[3]);
            }
    } else {
        if (lr < NH) {
            #pragma unroll
            for (int i = 0; i < 2; ++i)
                #pragma unroll
                for (int r = 0; r < 4; ++r) {
                    const int m = m0 + wave * 32 + i * 16 + lh * 4 + r;
                    wout[(size_t)m * NH + lr] = acc[i][0][r];
                }
        }
    }
}

// ---------------------------------------------------------------------------
// Score kernel (unchanged): bf16 MFMA, no LDS, 4 waves per 64x64 tile.
// ---------------------------------------------------------------------------
__global__ __launch_bounds__(256) void score_kernel(
    const unsigned short* __restrict__ qb, const unsigned short* __restrict__ kb,
    const float* __restrict__ wr, float* __restrict__ out)
{
    const int k0   = blockIdx.x * 64;
    const int q0   = blockIdx.y * 64;
    const int b    = blockIdx.z;
    const int tid  = threadIdx.x;
    const int wave = tid >> 6;
    const int lane = tid & 63;
    const int wm = wave >> 1, wn = wave & 1;
    const int lrow = lane & 15;
    const int ld8  = (lane >> 4) * 8;
    const int lr4  = (lane >> 4) * 4;

    const int qrow0 = q0 + wm * 32;
    const int krow0 = k0 + wn * 32;

    short8 bf[2][2];
    #pragma unroll
    for (int j = 0; j < 2; ++j)
        #pragma unroll
        for (int ks = 0; ks < 2; ++ks)
            bf[j][ks] = *reinterpret_cast<const short8*>(
                &kb[(size_t)(b * SDIM + krow0 + j * 16 + lrow) * DD + ks * 32 + ld8]);

    f32x4 zero4 = {0.f, 0.f, 0.f, 0.f};
    f32x4 oacc[2][2];
    #pragma unroll
    for (int i = 0; i < 2; ++i)
        #pragma unroll
        for (int j = 0; j < 2; ++j)
            oacc[i][j] = zero4;

    for (int h = 0; h < NH; ++h) {
        short8 af[2][2];
        #pragma unroll
        for (int i = 0; i < 2; ++i)
            #pragma unroll
            for (int ks = 0; ks < 2; ++ks)
                af[i][ks] = *reinterpret_cast<const short8*>(
                    &qb[((size_t)(b * SDIM + qrow0 + i * 16 + lrow) * NH + h) * DD
                        + ks * 32 + ld8]);

        f32x4 s[2][2];
        #pragma unroll
        for (int i = 0; i < 2; ++i)
            #pragma unroll
            for (int j = 0; j < 2; ++j)
                s[i][j] = zero4;

        #pragma unroll
        for (int ks = 0; ks < 2; ++ks)
            #pragma unroll
            for (int i = 0; i < 2; ++i)
                #pragma unroll
                for (int j = 0; j < 2; ++j)
                    s[i][j] = __builtin_amdgcn_mfma_f32_16x16x32_bf16(
                        af[i][ks], bf[j][ks], s[i][j], 0, 0, 0);

        #pragma unroll
        for (int i = 0; i < 2; ++i) {
            #pragma unroll
            for (int r = 0; r < 4; ++r) {
                const float wv = wr[(size_t)(b * SDIM + qrow0 + i * 16 + lr4 + r) * NH + h];
                #pragma unroll
                for (int j = 0; j < 2; ++j)
                    oacc[i][j][r] += wv * fmaxf(s[i][j][r], 0.f);
            }
        }
    }

    #pragma unroll
    for (int i = 0; i < 2; ++i)
        #pragma unroll
        for (int r = 0; r < 4; ++r)
            #pragma unroll
            for (int j = 0; j < 2; ++j)
                out[(size_t)(b * SDIM + qrow0 + i * 16 + lr4 + r) * SDIM
                    + krow0 + j * 16 + lrow] = oacc[i][j][r];
}

// ---------------------------------------------------------------------------
extern "C" void kernel_launch(void* const* d_in, const int* in_sizes, int n_in,
                              void* d_out, int out_size, void* d_ws, size_t ws_size,
                              hipStream_t stream) {
    const float* hs    = (const float*)d_in[0];
    const float* cosb  = (const float*)d_in[1];
    const float* sinb  = (const float*)d_in[2];
    const float* Wq    = (const float*)d_in[3];
    const float* Wk    = (const float*)d_in[4];
    const float* Ww    = (const float*)d_in[5];
    const float* gamma = (const float*)d_in[6];
    const float* beta  = (const float*)d_in[7];
    float* out = (float*)d_out;

    // hs2 (67 MB) lives in d_out's first half; score fully overwrites d_out later.
    unsigned short* hs2 = (unsigned short*)d_out;

    char* wsb = (char*)d_ws;
    unsigned short* qb  = (unsigned short*)wsb;                                  // [M,256] bf16
    unsigned short* kb  = (unsigned short*)(wsb + (size_t)BDIM * SDIM * 256 * 2);
    float*          ww  = (float*)(wsb + (size_t)BDIM * SDIM * 256 * 2
                                        + (size_t)BDIM * SDIM * DD * 2);
    unsigned short* Wt2 = (unsigned short*)(wsb + (size_t)BDIM * SDIM * 256 * 2
                                                 + (size_t)BDIM * SDIM * DD * 2
                                                 + (size_t)BDIM * SDIM * NH * 4);

    prep_w2<<<dim3(HIDDEN / 64, 6), 256, 0, stream>>>(Wq, Wk, Ww, Wt2);

    split_hs<<<(BDIM * SDIM * (HIDDEN / 4)) / 256, 256, 0, stream>>>(hs, hs2);

    proj_mfma<<<dim3((BDIM * SDIM) / 128, 6), 256, 0, stream>>>(
        hs2, Wt2, cosb, sinb, gamma, beta, qb, kb, ww);

    score_kernel<<<dim3(SDIM / 64, SDIM / 64, BDIM), 256, 0, stream>>>(
        qb, kb, ww, out);
}

// Round 5
// 110.620 us; speedup vs baseline: 4.1192x; 1.4893x over previous
//
#include <hip/hip_runtime.h>

#define BDIM 2
#define SDIM 4096
#define HIDDEN 2048
#define K2 4096          // split K: (hi,lo) interleaved
#define NH 4
#define DD 64
#define RR 32
constexpr float LN_EPS = 1e-5f;

typedef __attribute__((ext_vector_type(8))) short short8;   // 8 bf16 = 4 VGPRs
typedef __attribute__((ext_vector_type(4))) float f32x4;

// round-to-nearest-even f32 -> bf16
__device__ inline unsigned short f2bf(float f) {
    union { float f; unsigned u; } v; v.f = f;
    unsigned r = v.u + 0x7fff + ((v.u >> 16) & 1);
    return (unsigned short)(r >> 16);
}
__device__ inline float bf2f(unsigned short u) {
    union { unsigned u; float f; } v; v.u = ((unsigned)u) << 16;
    return v.f;
}

// async global -> LDS, 16 B per lane (wave-uniform LDS base + lane*16)
__device__ __forceinline__ void gload_lds16(const unsigned short* g, unsigned short* l) {
    __builtin_amdgcn_global_load_lds(
        (const __attribute__((address_space(1))) void*)g,
        (__attribute__((address_space(3))) void*)l, 16, 0, 0);
}

// ---------------------------------------------------------------------------
// split_hs: hs f32 [M,2048] -> hs2 bf16 [M,4096], (hi,lo) pairs along K,
// pre-swizzled per row (16B-slot XOR with m&7) for conflict-free proj staging.
// ---------------------------------------------------------------------------
__global__ __launch_bounds__(256) void split_hs(
    const float* __restrict__ hs, unsigned short* __restrict__ hs2)
{
    const int idx  = blockIdx.x * 256 + threadIdx.x;
    const int m    = idx >> 9;          // 512 slots per row
    const int slot = idx & 511;
    const float4 v = *reinterpret_cast<const float4*>(&hs[(size_t)m * HIDDEN + slot * 4]);
    unsigned short o[8];
    o[0] = f2bf(v.x); o[1] = f2bf(v.x - bf2f(o[0]));
    o[2] = f2bf(v.y); o[3] = f2bf(v.y - bf2f(o[2]));
    o[4] = f2bf(v.z); o[5] = f2bf(v.z - bf2f(o[4]));
    o[6] = f2bf(v.w); o[7] = f2bf(v.w - bf2f(o[6]));
    const int eoff = (slot * 8) ^ ((m & 7) << 3);
    *reinterpret_cast<short8*>(&hs2[(size_t)m * K2 + eoff]) =
        *reinterpret_cast<short8*>(o);
}

// ---------------------------------------------------------------------------
// prep_w2: Wt2 bf16 [384][4096], W[k][n] duplicated at k2=2k,2k+1, pre-swizzled.
// n-order: q 0..255, k 256..319, w 320..323, zeros to 383.
// ---------------------------------------------------------------------------
__global__ __launch_bounds__(256) void prep_w2(
    const float* __restrict__ Wq, const float* __restrict__ Wk,
    const float* __restrict__ Ww, unsigned short* __restrict__ Wt2)
{
    __shared__ float T[64][65];
    const int k0 = blockIdx.x * 64, n0 = blockIdx.y * 64;
    const int tid = threadIdx.x;
    {
        const int kr = tid >> 2;
        const int nq = (tid & 3) * 16;
        const int gk = k0 + kr;
        #pragma unroll
        for (int c = 0; c < 16; ++c) {
            const int n = n0 + nq + c;
            float v;
            if (n < 256)      v = Wq[(size_t)gk * 256 + n];
            else if (n < 320) v = Wk[(size_t)gk * 64 + (n - 256)];
            else if (n < 324) v = Ww[(size_t)gk * NH + (n - 320)];
            else              v = 0.f;
            T[kr][nq + c] = v;
        }
    }
    __syncthreads();
    {
        const int nr = tid >> 2;
        const int kc = (tid & 3) * 16;
        const int n  = n0 + nr;
        #pragma unroll
        for (int s = 0; s < 4; ++s) {
            const int kb = kc + s * 4;
            unsigned short e[8];
            #pragma unroll
            for (int t = 0; t < 4; ++t) {
                const unsigned short b = f2bf(T[kb + t][nr]);
                e[2 * t] = b; e[2 * t + 1] = b;
            }
            const int eoff = (2 * (k0 + kb)) ^ ((nr & 7) << 3);
            *reinterpret_cast<short8*>(&Wt2[(size_t)n * K2 + eoff]) =
                *reinterpret_cast<short8*>(e);
        }
    }
}

// ---------------------------------------------------------------------------
// proj_mfma (m97 structure): 128M x 64N, BK=128, grid (64,6), 4 waves of
// 32M x 64N. q-epilogue writes qout PRE-SWIZZLED (e ^= (m&7)<<3) so the
// score kernel can stage it via linear global_load_lds + XOR ds_read.
// ---------------------------------------------------------------------------
__global__ __launch_bounds__(256) void proj_mfma(
    const unsigned short* __restrict__ hs2, const unsigned short* __restrict__ Wt2,
    const float* __restrict__ cosb, const float* __restrict__ sinb,
    const float* __restrict__ gamma, const float* __restrict__ beta,
    unsigned short* __restrict__ qout, unsigned short* __restrict__ kout,
    float* __restrict__ wout)
{
    __shared__ unsigned short Asm[128 * 128];   // 32 KB
    __shared__ unsigned short Bsm[64 * 128];    // 16 KB

    const int m0   = blockIdx.x * 128;
    const int ng   = blockIdx.y;
    const int tid  = threadIdx.x;
    const int wave = tid >> 6, lane = tid & 63;
    const int lr = lane & 15, lh = lane >> 4;

    f32x4 acc[2][4];
    #pragma unroll
    for (int i = 0; i < 2; ++i)
        #pragma unroll
        for (int j = 0; j < 4; ++j)
            acc[i][j] = (f32x4){0.f, 0.f, 0.f, 0.f};

    const int srow  = tid >> 4;
    const int sslot = tid & 15;
    const unsigned short* gA = hs2 + (size_t)(m0 + srow) * K2 + sslot * 8;
    const unsigned short* gB = Wt2 + (size_t)(ng * 64 + srow) * K2 + sslot * 8;
    unsigned short* lA = Asm + tid * 8;
    unsigned short* lB = Bsm + tid * 8;

    for (int k0 = 0; k0 < K2; k0 += 128) {
        #pragma unroll
        for (int i = 0; i < 8; ++i)
            gload_lds16(gA + (size_t)i * 16 * K2 + k0, lA + i * 2048);
        #pragma unroll
        for (int i = 0; i < 4; ++i)
            gload_lds16(gB + (size_t)i * 16 * K2 + k0, lB + i * 2048);
        __syncthreads();

        #pragma unroll
        for (int kk = 0; kk < 4; ++kk) {
            short8 av[2], bv[4];
            #pragma unroll
            for (int i = 0; i < 2; ++i) {
                const int row = wave * 32 + i * 16 + lr;
                const int off = (row * 128 + kk * 32 + lh * 8) ^ ((row & 7) << 3);
                av[i] = *reinterpret_cast<const short8*>(&Asm[off]);
            }
            #pragma unroll
            for (int j = 0; j < 4; ++j) {
                const int row = j * 16 + lr;
                const int off = (row * 128 + kk * 32 + lh * 8) ^ ((row & 7) << 3);
                bv[j] = *reinterpret_cast<const short8*>(&Bsm[off]);
            }
            #pragma unroll
            for (int i = 0; i < 2; ++i)
                #pragma unroll
                for (int j = 0; j < 4; ++j)
                    acc[i][j] = __builtin_amdgcn_mfma_f32_16x16x32_bf16(
                        av[i], bv[j], acc[i][j], 0, 0, 0);
        }
        __syncthreads();
    }

    // ---- epilogue. C/D: col = lr + j*16, row = wave*32 + i*16 + lh*4 + r
    if (ng < 4) {
        #pragma unroll
        for (int i = 0; i < 2; ++i)
            #pragma unroll
            for (int r = 0; r < 4; ++r) {
                const int m = m0 + wave * 32 + i * 16 + lh * 4 + r;
                const float x0 = acc[i][0][r], x1 = acc[i][1][r];
                const float c0 = cosb[(size_t)m * RR + lr];
                const float s0 = sinb[(size_t)m * RR + lr];
                const float c1 = cosb[(size_t)m * RR + 16 + lr];
                const float s1 = sinb[(size_t)m * RR + 16 + lr];
                const int sw = (m & 7) << 3;   // pre-swizzle for score staging
                const size_t rowb = (size_t)m * (NH * DD);
                const int e0 = ng * DD + lr;
                qout[rowb + (e0 ^ sw)]        = f2bf(x0 * c0 - x1 * s0);
                qout[rowb + ((e0 + 16) ^ sw)] = f2bf(x1 * c1 + x0 * s1);
                qout[rowb + ((e0 + 32) ^ sw)] = f2bf(acc[i][2][r]);
                qout[rowb + ((e0 + 48) ^ sw)] = f2bf(acc[i][3][r]);
            }
    } else if (ng == 4) {
        float g[4], bb[4];
        #pragma unroll
        for (int j = 0; j < 4; ++j) { g[j] = gamma[j * 16 + lr]; bb[j] = beta[j * 16 + lr]; }
        #pragma unroll
        for (int i = 0; i < 2; ++i)
            #pragma unroll
            for (int r = 0; r < 4; ++r) {
                float t1 = 0.f, t2 = 0.f;
                #pragma unroll
                for (int j = 0; j < 4; ++j) {
                    const float a = acc[i][j][r];
                    t1 += a; t2 += a * a;
                }
                #pragma unroll
                for (int msk = 1; msk < 16; msk <<= 1) {
                    t1 += __shfl_xor(t1, msk, 64);
                    t2 += __shfl_xor(t2, msk, 64);
                }
                const float mu  = t1 * (1.f / 64.f);
                const float var = t2 * (1.f / 64.f) - mu * mu;
                const float rs  = rsqrtf(var + LN_EPS);
                const int m = m0 + wave * 32 + i * 16 + lh * 4 + r;
                float x[4];
                #pragma unroll
                for (int j = 0; j < 4; ++j)
                    x[j] = (acc[i][j][r] - mu) * rs * g[j] + bb[j];
                const float c0 = cosb[(size_t)m * RR + lr];
                const float s0 = sinb[(size_t)m * RR + lr];
                const float c1 = cosb[(size_t)m * RR + 16 + lr];
                const float s1 = sinb[(size_t)m * RR + 16 + lr];
                const float n0 = x[0] * c0 - x[1] * s0;
                const float n1 = x[1] * c1 + x[0] * s1;
                const size_t base = (size_t)m * DD + lr;
                kout[base]      = f2bf(n0);
                kout[base + 16] = f2bf(n1);
                kout[base + 32] = f2bf(x[2]);
                kout[base + 48] = f2bf(x[3]);
            }
    } else {
        if (lr < NH) {
            #pragma unroll
            for (int i = 0; i < 2; ++i)
                #pragma unroll
                for (int r = 0; r < 4; ++r) {
                    const int m = m0 + wave * 32 + i * 16 + lh * 4 + r;
                    wout[(size_t)m * NH + lr] = acc[i][0][r];
                }
        }
    }
}

// ---------------------------------------------------------------------------
// score v3: grid (8 k-chunks, 64 q-tiles, B). Q-tile (64x256 bf16) staged in
// LDS once (swizzled), w-tile once; 8 k-subtiles of 64 cols with 2-deep
// register prefetch of h-invariant K fragments. 4 waves in 2x2 per subtile.
// ---------------------------------------------------------------------------
__global__ __launch_bounds__(256) void score_kernel(
    const unsigned short* __restrict__ qb, const unsigned short* __restrict__ kb,
    const float* __restrict__ wr, float* __restrict__ out)
{
    __shared__ unsigned short Qlds[64 * 256];   // 32 KB, swizzled slots
    __shared__ float Wlds[64 * 4];              // 1 KB

    const int kc  = blockIdx.x;          // 512-col k chunk
    const int q0  = blockIdx.y * 64;
    const int b   = blockIdx.z;
    const int tid = threadIdx.x;
    const int wave = tid >> 6, lane = tid & 63;
    const int wm = wave >> 1, wn = wave & 1;
    const int lr = lane & 15, lh = lane >> 4;
    const int kbase = kc * 512;

    // stage Q tile (pre-swizzled in qb -> linear LDS)
    #pragma unroll
    for (int i = 0; i < 8; ++i) {
        const int id   = i * 256 + tid;
        const int row  = id >> 5;        // 32 slots of 16B per row
        const int slot = id & 31;
        gload_lds16(qb + (size_t)(b * SDIM + q0 + row) * 256 + slot * 8,
                    Qlds + id * 8);
    }
    Wlds[tid] = wr[(size_t)(b * SDIM + q0) * NH + tid];
    __syncthreads();   // drains vmcnt (global_load_lds) + lds write

    // w per lane: f32x4 over h for each of the 8 owned rows
    f32x4 wreg[2][4];
    #pragma unroll
    for (int i = 0; i < 2; ++i)
        #pragma unroll
        for (int r = 0; r < 4; ++r) {
            const int row = wm * 32 + i * 16 + lh * 4 + r;
            wreg[i][r] = *reinterpret_cast<const f32x4*>(&Wlds[row * 4]);
        }

    // K fragment loader (h-invariant)
    const size_t krow_base = (size_t)(b * SDIM + kbase + wn * 32);
    #define LOADK(dst, st)                                                      \
        _Pragma("unroll")                                                       \
        for (int j = 0; j < 2; ++j)                                             \
            _Pragma("unroll")                                                   \
            for (int ks = 0; ks < 2; ++ks)                                      \
                dst[j][ks] = *reinterpret_cast<const short8*>(                  \
                    &kb[(krow_base + (st) * 64 + j * 16 + lr) * DD + ks * 32 + lh * 8]);

    short8 kcur[2][2], knx[2][2];
    LOADK(kcur, 0)

    for (int st = 0; st < 8; ++st) {
        if (st < 7) { LOADK(knx, st + 1) }

        f32x4 o[2][2];
        #pragma unroll
        for (int i = 0; i < 2; ++i)
            #pragma unroll
            for (int j = 0; j < 2; ++j)
                o[i][j] = (f32x4){0.f, 0.f, 0.f, 0.f};

        #pragma unroll
        for (int h = 0; h < NH; ++h) {
            // Q frags from LDS (XOR-swizzled)
            short8 qf[2][2];
            #pragma unroll
            for (int i = 0; i < 2; ++i)
                #pragma unroll
                for (int ks = 0; ks < 2; ++ks) {
                    const int row  = wm * 32 + i * 16 + lr;
                    const int slot = (h * 8 + ks * 4 + lh) ^ (row & 7);
                    qf[i][ks] = *reinterpret_cast<const short8*>(
                        &Qlds[row * 256 + slot * 8]);
                }
            f32x4 s[2][2];
            #pragma unroll
            for (int i = 0; i < 2; ++i)
                #pragma unroll
                for (int j = 0; j < 2; ++j)
                    s[i][j] = (f32x4){0.f, 0.f, 0.f, 0.f};
            #pragma unroll
            for (int ks = 0; ks < 2; ++ks)
                #pragma unroll
                for (int i = 0; i < 2; ++i)
                    #pragma unroll
                    for (int j = 0; j < 2; ++j)
                        s[i][j] = __builtin_amdgcn_mfma_f32_16x16x32_bf16(
                            qf[i][ks], kcur[j][ks], s[i][j], 0, 0, 0);
            #pragma unroll
            for (int i = 0; i < 2; ++i)
                #pragma unroll
                for (int j = 0; j < 2; ++j)
                    #pragma unroll
                    for (int r = 0; r < 4; ++r)
                        o[i][j][r] += wreg[i][r][h] * fmaxf(s[i][j][r], 0.f);
        }

        // store subtile
        #pragma unroll
        for (int i = 0; i < 2; ++i)
            #pragma unroll
            for (int r = 0; r < 4; ++r)
                #pragma unroll
                for (int j = 0; j < 2; ++j)
                    out[(size_t)(b * SDIM + q0 + wm * 32 + i * 16 + lh * 4 + r) * SDIM
                        + kbase + st * 64 + wn * 32 + j * 16 + lr] = o[i][j][r];

        #pragma unroll
        for (int j = 0; j < 2; ++j)
            #pragma unroll
            for (int ks = 0; ks < 2; ++ks)
                kcur[j][ks] = knx[j][ks];
    }
    #undef LOADK
}

// ---------------------------------------------------------------------------
extern "C" void kernel_launch(void* const* d_in, const int* in_sizes, int n_in,
                              void* d_out, int out_size, void* d_ws, size_t ws_size,
                              hipStream_t stream) {
    const float* hs    = (const float*)d_in[0];
    const float* cosb  = (const float*)d_in[1];
    const float* sinb  = (const float*)d_in[2];
    const float* Wq    = (const float*)d_in[3];
    const float* Wk    = (const float*)d_in[4];
    const float* Ww    = (const float*)d_in[5];
    const float* gamma = (const float*)d_in[6];
    const float* beta  = (const float*)d_in[7];
    float* out = (float*)d_out;

    // hs2 (67 MB) lives in d_out; dead after proj, overwritten by score.
    unsigned short* hs2 = (unsigned short*)d_out;

    char* wsb = (char*)d_ws;
    unsigned short* qb  = (unsigned short*)wsb;                                  // [M,256] bf16
    unsigned short* kb  = (unsigned short*)(wsb + (size_t)BDIM * SDIM * 256 * 2);
    float*          ww  = (float*)(wsb + (size_t)BDIM * SDIM * 256 * 2
                                        + (size_t)BDIM * SDIM * DD * 2);
    unsigned short* Wt2 = (unsigned short*)(wsb + (size_t)BDIM * SDIM * 256 * 2
                                                 + (size_t)BDIM * SDIM * DD * 2
                                                 + (size_t)BDIM * SDIM * NH * 4);

    prep_w2<<<dim3(HIDDEN / 64, 6), 256, 0, stream>>>(Wq, Wk, Ww, Wt2);

    split_hs<<<(BDIM * SDIM * (HIDDEN / 4)) / 256, 256, 0, stream>>>(hs, hs2);

    proj_mfma<<<dim3((BDIM * SDIM) / 128, 6), 256, 0, stream>>>(
        hs2, Wt2, cosb, sinb, gamma, beta, qb, kb, ww);

    score_kernel<<<dim3(SDIM / 512, SDIM / 64, BDIM), 256, 0, stream>>>(
        qb, kb, ww, out);
}

// Round 6
// 85.633 us; speedup vs baseline: 5.3212x; 1.2918x over previous
//
#include <hip/hip_runtime.h>

#define BDIM 2
#define SDIM 4096
#define HIDDEN 2048
#define NH 4
#define DD 64
#define RR 32
constexpr float LN_EPS = 1e-5f;

typedef _Float16 half8 __attribute__((ext_vector_type(8)));   // 8 f16 = 4 VGPRs
typedef __attribute__((ext_vector_type(4))) float f32x4;

// async global -> LDS, 16 B per lane (wave-uniform LDS base + lane*16)
__device__ __forceinline__ void gload_lds16(const void* g, void* l) {
    __builtin_amdgcn_global_load_lds(
        (const __attribute__((address_space(1))) void*)g,
        (__attribute__((address_space(3))) void*)l, 16, 0, 0);
}

// ---------------------------------------------------------------------------
// split_hs: hs f32 [M,2048] -> hs2 f16 [M,2048], pre-swizzled per row
// (16B-slot XOR with m&7) so linear global_load_lds + XOR ds_read is
// conflict-free (rule #21). One thread per 8-elem slot. Grid 16384 x 256.
// ---------------------------------------------------------------------------
__global__ __launch_bounds__(256) void split_hs(
    const float* __restrict__ hs, _Float16* __restrict__ hs2)
{
    const int idx  = blockIdx.x * 256 + threadIdx.x;
    const int m    = idx >> 8;          // 256 slots per row
    const int slot = idx & 255;
    const float4 v0 = *reinterpret_cast<const float4*>(&hs[(size_t)m * HIDDEN + slot * 8]);
    const float4 v1 = *reinterpret_cast<const float4*>(&hs[(size_t)m * HIDDEN + slot * 8 + 4]);
    _Float16 o[8];
    o[0] = (_Float16)v0.x; o[1] = (_Float16)v0.y;
    o[2] = (_Float16)v0.z; o[3] = (_Float16)v0.w;
    o[4] = (_Float16)v1.x; o[5] = (_Float16)v1.y;
    o[6] = (_Float16)v1.z; o[7] = (_Float16)v1.w;
    const int eoff = (slot * 8) ^ ((m & 7) << 3);
    *reinterpret_cast<half8*>(&hs2[(size_t)m * HIDDEN + eoff]) =
        *reinterpret_cast<half8*>(o);
}

// ---------------------------------------------------------------------------
// prep_w2: Wt2 f16 [384][2048] transposed k-contiguous, pre-swizzled.
// n-order: q 0..255, k 256..319, w 320..323, zeros to 383. Grid (32, 6).
// ---------------------------------------------------------------------------
__global__ __launch_bounds__(256) void prep_w2(
    const float* __restrict__ Wq, const float* __restrict__ Wk,
    const float* __restrict__ Ww, _Float16* __restrict__ Wt2)
{
    __shared__ float T[64][65];
    const int k0 = blockIdx.x * 64, n0 = blockIdx.y * 64;
    const int tid = threadIdx.x;
    {
        const int kr = tid >> 2;
        const int nq = (tid & 3) * 16;
        const int gk = k0 + kr;
        #pragma unroll
        for (int c = 0; c < 16; ++c) {
            const int n = n0 + nq + c;
            float v;
            if (n < 256)      v = Wq[(size_t)gk * 256 + n];
            else if (n < 320) v = Wk[(size_t)gk * 64 + (n - 256)];
            else if (n < 324) v = Ww[(size_t)gk * NH + (n - 320)];
            else              v = 0.f;
            T[kr][nq + c] = v;
        }
    }
    __syncthreads();
    {
        const int nr = tid >> 2;
        const int kc = (tid & 3) * 16;
        const int n  = n0 + nr;
        #pragma unroll
        for (int s = 0; s < 2; ++s) {
            const int kb = kc + s * 8;
            _Float16 e[8];
            #pragma unroll
            for (int t = 0; t < 8; ++t) e[t] = (_Float16)T[kb + t][nr];
            const int eoff = (k0 + kb) ^ ((nr & 7) << 3);
            *reinterpret_cast<half8*>(&Wt2[(size_t)n * HIDDEN + eoff]) =
                *reinterpret_cast<half8*>(e);
        }
    }
}

// ---------------------------------------------------------------------------
// proj_mfma (m97 structure, f16): 128M x 64N, BK=128, K=2048, grid (64,6),
// 4 waves of 32M x 64N. q-epilogue writes qout PRE-SWIZZLED (e ^= (m&7)<<3)
// for the score kernel's linear global_load_lds + XOR ds_read.
// ---------------------------------------------------------------------------
__global__ __launch_bounds__(256) void proj_mfma(
    const _Float16* __restrict__ hs2, const _Float16* __restrict__ Wt2,
    const float* __restrict__ cosb, const float* __restrict__ sinb,
    const float* __restrict__ gamma, const float* __restrict__ beta,
    _Float16* __restrict__ qout, _Float16* __restrict__ kout,
    float* __restrict__ wout)
{
    __shared__ _Float16 Asm[128 * 128];   // 32 KB
    __shared__ _Float16 Bsm[64 * 128];    // 16 KB

    const int m0   = blockIdx.x * 128;
    const int ng   = blockIdx.y;
    const int tid  = threadIdx.x;
    const int wave = tid >> 6, lane = tid & 63;
    const int lr = lane & 15, lh = lane >> 4;

    f32x4 acc[2][4];
    #pragma unroll
    for (int i = 0; i < 2; ++i)
        #pragma unroll
        for (int j = 0; j < 4; ++j)
            acc[i][j] = (f32x4){0.f, 0.f, 0.f, 0.f};

    const int srow  = tid >> 4;
    const int sslot = tid & 15;
    const _Float16* gA = hs2 + (size_t)(m0 + srow) * HIDDEN + sslot * 8;
    const _Float16* gB = Wt2 + (size_t)(ng * 64 + srow) * HIDDEN + sslot * 8;
    _Float16* lA = Asm + tid * 8;
    _Float16* lB = Bsm + tid * 8;

    for (int k0 = 0; k0 < HIDDEN; k0 += 128) {
        #pragma unroll
        for (int i = 0; i < 8; ++i)
            gload_lds16(gA + (size_t)i * 16 * HIDDEN + k0, lA + i * 2048);
        #pragma unroll
        for (int i = 0; i < 4; ++i)
            gload_lds16(gB + (size_t)i * 16 * HIDDEN + k0, lB + i * 2048);
        __syncthreads();

        #pragma unroll
        for (int kk = 0; kk < 4; ++kk) {
            half8 av[2], bv[4];
            #pragma unroll
            for (int i = 0; i < 2; ++i) {
                const int row = wave * 32 + i * 16 + lr;
                const int off = (row * 128 + kk * 32 + lh * 8) ^ ((row & 7) << 3);
                av[i] = *reinterpret_cast<const half8*>(&Asm[off]);
            }
            #pragma unroll
            for (int j = 0; j < 4; ++j) {
                const int row = j * 16 + lr;
                const int off = (row * 128 + kk * 32 + lh * 8) ^ ((row & 7) << 3);
                bv[j] = *reinterpret_cast<const half8*>(&Bsm[off]);
            }
            #pragma unroll
            for (int i = 0; i < 2; ++i)
                #pragma unroll
                for (int j = 0; j < 4; ++j)
                    acc[i][j] = __builtin_amdgcn_mfma_f32_16x16x32_f16(
                        av[i], bv[j], acc[i][j], 0, 0, 0);
        }
        __syncthreads();
    }

    // ---- epilogue. C/D: col = lr + j*16, row = wave*32 + i*16 + lh*4 + r
    if (ng < 4) {
        #pragma unroll
        for (int i = 0; i < 2; ++i)
            #pragma unroll
            for (int r = 0; r < 4; ++r) {
                const int m = m0 + wave * 32 + i * 16 + lh * 4 + r;
                const float x0 = acc[i][0][r], x1 = acc[i][1][r];
                const float c0 = cosb[(size_t)m * RR + lr];
                const float s0 = sinb[(size_t)m * RR + lr];
                const float c1 = cosb[(size_t)m * RR + 16 + lr];
                const float s1 = sinb[(size_t)m * RR + 16 + lr];
                const int sw = (m & 7) << 3;   // pre-swizzle for score staging
                const size_t rowb = (size_t)m * (NH * DD);
                const int e0 = ng * DD + lr;
                qout[rowb + (e0 ^ sw)]        = (_Float16)(x0 * c0 - x1 * s0);
                qout[rowb + ((e0 + 16) ^ sw)] = (_Float16)(x1 * c1 + x0 * s1);
                qout[rowb + ((e0 + 32) ^ sw)] = (_Float16)acc[i][2][r];
                qout[rowb + ((e0 + 48) ^ sw)] = (_Float16)acc[i][3][r];
            }
    } else if (ng == 4) {
        float g[4], bb[4];
        #pragma unroll
        for (int j = 0; j < 4; ++j) { g[j] = gamma[j * 16 + lr]; bb[j] = beta[j * 16 + lr]; }
        #pragma unroll
        for (int i = 0; i < 2; ++i)
            #pragma unroll
            for (int r = 0; r < 4; ++r) {
                float t1 = 0.f, t2 = 0.f;
                #pragma unroll
                for (int j = 0; j < 4; ++j) {
                    const float a = acc[i][j][r];
                    t1 += a; t2 += a * a;
                }
                #pragma unroll
                for (int msk = 1; msk < 16; msk <<= 1) {
                    t1 += __shfl_xor(t1, msk, 64);
                    t2 += __shfl_xor(t2, msk, 64);
                }
                const float mu  = t1 * (1.f / 64.f);
                const float var = t2 * (1.f / 64.f) - mu * mu;
                const float rs  = rsqrtf(var + LN_EPS);
                const int m = m0 + wave * 32 + i * 16 + lh * 4 + r;
                float x[4];
                #pragma unroll
                for (int j = 0; j < 4; ++j)
                    x[j] = (acc[i][j][r] - mu) * rs * g[j] + bb[j];
                const float c0 = cosb[(size_t)m * RR + lr];
                const float s0 = sinb[(size_t)m * RR + lr];
                const float c1 = cosb[(size_t)m * RR + 16 + lr];
                const float s1 = sinb[(size_t)m * RR + 16 + lr];
                const float y0 = x[0] * c0 - x[1] * s0;
                const float y1 = x[1] * c1 + x[0] * s1;
                const size_t base = (size_t)m * DD + lr;
                kout[base]      = (_Float16)y0;
                kout[base + 16] = (_Float16)y1;
                kout[base + 32] = (_Float16)x[2];
                kout[base + 48] = (_Float16)x[3];
            }
    } else {
        if (lr < NH) {
            #pragma unroll
            for (int i = 0; i < 2; ++i)
                #pragma unroll
                for (int r = 0; r < 4; ++r) {
                    const int m = m0 + wave * 32 + i * 16 + lh * 4 + r;
                    wout[(size_t)m * NH + lr] = acc[i][0][r];
                }
        }
    }
}

// ---------------------------------------------------------------------------
// score v3 (f16): grid (8 k-chunks, 64 q-tiles, B). Q-tile (64x256 f16)
// staged in LDS once (swizzled), w-tile once; 8 k-subtiles with 2-deep
// register prefetch of h-invariant K fragments. 4 waves in 2x2 per subtile.
// ---------------------------------------------------------------------------
__global__ __launch_bounds__(256) void score_kernel(
    const _Float16* __restrict__ qb, const _Float16* __restrict__ kb,
    const float* __restrict__ wr, float* __restrict__ out)
{
    __shared__ _Float16 Qlds[64 * 256];   // 32 KB, swizzled slots
    __shared__ float Wlds[64 * 4];        // 1 KB

    const int kc  = blockIdx.x;          // 512-col k chunk
    const int q0  = blockIdx.y * 64;
    const int b   = blockIdx.z;
    const int tid = threadIdx.x;
    const int wave = tid >> 6, lane = tid & 63;
    const int wm = wave >> 1, wn = wave & 1;
    const int lr = lane & 15, lh = lane >> 4;
    const int kbase = kc * 512;

    // stage Q tile (pre-swizzled in qb -> linear LDS)
    #pragma unroll
    for (int i = 0; i < 8; ++i) {
        const int id   = i * 256 + tid;
        const int row  = id >> 5;        // 32 slots of 16B per row
        const int slot = id & 31;
        gload_lds16(qb + (size_t)(b * SDIM + q0 + row) * 256 + slot * 8,
                    Qlds + id * 8);
    }
    Wlds[tid] = wr[(size_t)(b * SDIM + q0) * NH + tid];
    __syncthreads();   // drains vmcnt (global_load_lds) + lds write

    // w per lane: f32x4 over h for each of the 8 owned rows
    f32x4 wreg[2][4];
    #pragma unroll
    for (int i = 0; i < 2; ++i)
        #pragma unroll
        for (int r = 0; r < 4; ++r) {
            const int row = wm * 32 + i * 16 + lh * 4 + r;
            wreg[i][r] = *reinterpret_cast<const f32x4*>(&Wlds[row * 4]);
        }

    // K fragment loader (h-invariant)
    const size_t krow_base = (size_t)(b * SDIM + kbase + wn * 32);
    #define LOADK(dst, st)                                                      \
        _Pragma("unroll")                                                       \
        for (int j = 0; j < 2; ++j)                                             \
            _Pragma("unroll")                                                   \
            for (int ks = 0; ks < 2; ++ks)                                      \
                dst[j][ks] = *reinterpret_cast<const half8*>(                   \
                    &kb[(krow_base + (st) * 64 + j * 16 + lr) * DD + ks * 32 + lh * 8]);

    half8 kcur[2][2], knx[2][2];
    LOADK(kcur, 0)

    for (int st = 0; st < 8; ++st) {
        if (st < 7) { LOADK(knx, st + 1) }

        f32x4 o[2][2];
        #pragma unroll
        for (int i = 0; i < 2; ++i)
            #pragma unroll
            for (int j = 0; j < 2; ++j)
                o[i][j] = (f32x4){0.f, 0.f, 0.f, 0.f};

        #pragma unroll
        for (int h = 0; h < NH; ++h) {
            half8 qf[2][2];
            #pragma unroll
            for (int i = 0; i < 2; ++i)
                #pragma unroll
                for (int ks = 0; ks < 2; ++ks) {
                    const int row  = wm * 32 + i * 16 + lr;
                    const int slot = (h * 8 + ks * 4 + lh) ^ (row & 7);
                    qf[i][ks] = *reinterpret_cast<const half8*>(
                        &Qlds[row * 256 + slot * 8]);
                }
            f32x4 s[2][2];
            #pragma unroll
            for (int i = 0; i < 2; ++i)
                #pragma unroll
                for (int j = 0; j < 2; ++j)
                    s[i][j] = (f32x4){0.f, 0.f, 0.f, 0.f};
            #pragma unroll
            for (int ks = 0; ks < 2; ++ks)
                #pragma unroll
                for (int i = 0; i < 2; ++i)
                    #pragma unroll
                    for (int j = 0; j < 2; ++j)
                        s[i][j] = __builtin_amdgcn_mfma_f32_16x16x32_f16(
                            qf[i][ks], kcur[j][ks], s[i][j], 0, 0, 0);
            #pragma unroll
            for (int i = 0; i < 2; ++i)
                #pragma unroll
                for (int j = 0; j < 2; ++j)
                    #pragma unroll
                    for (int r = 0; r < 4; ++r)
                        o[i][j][r] += wreg[i][r][h] * fmaxf(s[i][j][r], 0.f);
        }

        // store subtile (scalar stores are lane-coalesced: lr = consecutive cols)
        #pragma unroll
        for (int i = 0; i < 2; ++i)
            #pragma unroll
            for (int r = 0; r < 4; ++r)
                #pragma unroll
                for (int j = 0; j < 2; ++j)
                    out[(size_t)(b * SDIM + q0 + wm * 32 + i * 16 + lh * 4 + r) * SDIM
                        + kbase + st * 64 + wn * 32 + j * 16 + lr] = o[i][j][r];

        #pragma unroll
        for (int j = 0; j < 2; ++j)
            #pragma unroll
            for (int ks = 0; ks < 2; ++ks)
                kcur[j][ks] = knx[j][ks];
    }
    #undef LOADK
}

// ---------------------------------------------------------------------------
extern "C" void kernel_launch(void* const* d_in, const int* in_sizes, int n_in,
                              void* d_out, int out_size, void* d_ws, size_t ws_size,
                              hipStream_t stream) {
    const float* hs    = (const float*)d_in[0];
    const float* cosb  = (const float*)d_in[1];
    const float* sinb  = (const float*)d_in[2];
    const float* Wq    = (const float*)d_in[3];
    const float* Wk    = (const float*)d_in[4];
    const float* Ww    = (const float*)d_in[5];
    const float* gamma = (const float*)d_in[6];
    const float* beta  = (const float*)d_in[7];
    float* out = (float*)d_out;

    // hs2 (33.5 MB f16) lives in d_out; dead after proj, overwritten by score.
    _Float16* hs2 = (_Float16*)d_out;

    char* wsb = (char*)d_ws;
    _Float16* qb  = (_Float16*)wsb;                                   // [M,256] f16
    _Float16* kb  = (_Float16*)(wsb + (size_t)BDIM * SDIM * 256 * 2); // [M,64] f16
    float*    ww  = (float*)(wsb + (size_t)BDIM * SDIM * 256 * 2
                                  + (size_t)BDIM * SDIM * DD * 2);
    _Float16* Wt2 = (_Float16*)(wsb + (size_t)BDIM * SDIM * 256 * 2
                                     + (size_t)BDIM * SDIM * DD * 2
                                     + (size_t)BDIM * SDIM * NH * 4);

    prep_w2<<<dim3(HIDDEN / 64, 6), 256, 0, stream>>>(Wq, Wk, Ww, Wt2);

    split_hs<<<(BDIM * SDIM * (HIDDEN / 8)) / 256, 256, 0, stream>>>(hs, hs2);

    proj_mfma<<<dim3((BDIM * SDIM) / 128, 6), 256, 0, stream>>>(
        hs2, Wt2, cosb, sinb, gamma, beta, qb, kb, ww);

    score_kernel<<<dim3(SDIM / 512, SDIM / 64, BDIM), 256, 0, stream>>>(
        qb, kb, ww, out);
}